// Round 8
// baseline (346.935 us; speedup 1.0000x reference)
//
#include <hip/hip_runtime.h>

typedef unsigned int u32;
typedef unsigned short u16;
typedef __attribute__((ext_vector_type(8))) short bf16x8;
typedef __attribute__((ext_vector_type(4))) float f32x4;

constexpr int BATCH = 32;
constexpr int DIM   = 256;
constexpr int NPTS  = 512;
constexpr int NH    = 8;
constexpr int KD    = 16;
constexpr int DHEAD = 64;
constexpr int NH_KD = 128;
constexpr int DH    = 512;

__device__ __forceinline__ float bflo(u32 u){ return __uint_as_float(u << 16); }
__device__ __forceinline__ float bfhi(u32 u){ return __uint_as_float(u & 0xffff0000u); }
__device__ __forceinline__ float bf2f(u16 u){ return __uint_as_float(((u32)u) << 16); }
__device__ __forceinline__ u32 f2bf_bits(float f){
  u32 u = __float_as_uint(f);
  return (u + 0x7fffu + ((u >> 16) & 1u)) >> 16;
}
__device__ __forceinline__ u32 pack2bf(float a, float b){
  return f2bf_bits(a) | (f2bf_bits(b) << 16);
}

union B8 { bf16x8 v; uint2 u2[2]; uint4 u4; };

// ---------------------------------------------------------------------------
// K0: fold scale into weights, convert to bf16.
// ---------------------------------------------------------------------------
__global__ __launch_bounds__(256) void k_prep(
    const float* __restrict__ wq, const float* __restrict__ sq,
    const float* __restrict__ wp, const float* __restrict__ sp,
    u32* __restrict__ wqb, u32* __restrict__ pwb)
{
  int t = blockIdx.x * 256 + threadIdx.x;
  if (t < 98304){                      // 768*256/2
    int i = 2*t;
    float s = sq[i >> 8];
    wqb[t] = pack2bf(wq[i]*s, wq[i+1]*s);
  } else {
    int j = t - 98304;                 // 256*512/2
    int i = 2*j;
    float s = sp[i >> 9];
    pwb[j] = pack2bf(wp[i]*s, wp[i+1]*s);
  }
}

// ---------------------------------------------------------------------------
// K1: qkv MFMA GEMM. C[o 768][n 512] per batch, K=256.
// v stored with m-columns permuted within 32-blocks so k_attn's transposed
// score registers directly form the PV A-fragment:
//   p = (n&~31) | (n&3) | (((n>>4)&1)<<2) | (((n>>2)&3)<<3)
// ---------------------------------------------------------------------------
__global__ __launch_bounds__(256) void k_qkv(
    const float* __restrict__ x, const u16* __restrict__ wqb,
    const float* __restrict__ bias,
    u16* __restrict__ qfb, u16* __restrict__ kb, u16* __restrict__ vb)
{
  __shared__ __align__(16) u16 Xl[128*36];

  const int Mblk = blockIdx.x, Nblk = blockIdx.y, b = blockIdx.z;
  const int tid = threadIdx.x, wave = tid >> 6, lane = tid & 63;
  const int wm = wave >> 1, wn = wave & 1;
  const int c = lane & 15, q = lane >> 4;
  const int Mbase = Mblk*128 + wm*64;

  f32x4 acc[4][4];
  #pragma unroll
  for (int mt = 0; mt < 4; mt++){
    f32x4 bi;
    #pragma unroll
    for (int r = 0; r < 4; r++) bi[r] = bias[Mbase + mt*16 + q*4 + r];
    #pragma unroll
    for (int nt = 0; nt < 4; nt++) acc[mt][nt] = bi;
  }

  const float* xb = x + (size_t)b*DIM*NPTS + Nblk*128;

  for (int kc8 = 0; kc8 < 8; kc8++){
    const int kc = kc8*32;
    __syncthreads();
    #pragma unroll
    for (int it = 0; it < 4; it++){
      int n2 = 2*((tid & 31) + 32*(it & 1));
      int cc = 2*((tid >> 5) + 8*(it >> 1));
      const float* xr = xb + (size_t)(kc + cc)*NPTS + n2;
      float2 A = *(const float2*)xr;
      float2 Bv = *(const float2*)(xr + NPTS);
      *(u32*)(Xl + (size_t)n2*36 + cc)     = pack2bf(A.x, Bv.x);
      *(u32*)(Xl + (size_t)(n2+1)*36 + cc) = pack2bf(A.y, Bv.y);
    }
    __syncthreads();

    bf16x8 aW[4];
    #pragma unroll
    for (int mt = 0; mt < 4; mt++)
      aW[mt] = *(const bf16x8*)(wqb + (size_t)(Mbase + mt*16 + c)*256 + kc + q*8);
    B8 bX[4];
    #pragma unroll
    for (int nt = 0; nt < 4; nt++){
      const u16* base = Xl + (size_t)(wn*64 + nt*16 + c)*36 + q*8;
      bX[nt].u2[0] = *(const uint2*)(base);
      bX[nt].u2[1] = *(const uint2*)(base + 4);
    }
    #pragma unroll
    for (int mt = 0; mt < 4; mt++)
      #pragma unroll
      for (int nt = 0; nt < 4; nt++)
        acc[mt][nt] = __builtin_amdgcn_mfma_f32_16x16x32_bf16(
            aW[mt], bX[nt].v, acc[mt][nt], 0, 0, 0);
  }

  #pragma unroll
  for (int mt = 0; mt < 4; mt++){
    const int ob = wm*64 + mt*16 + q*4;
    #pragma unroll
    for (int nt = 0; nt < 4; nt++){
      const int n = Nblk*128 + wn*64 + nt*16 + c;
      #pragma unroll
      for (int r = 0; r < 4; r++){
        u16 bv = (u16)f2bf_bits(acc[mt][nt][r]);
        int ol = ob + r;
        if (Mblk == 0){
          qfb[((size_t)b*NH_KD + ol)*NPTS + n] = bv;
        } else if (Mblk == 1){
          kb[(((size_t)b*NH + (ol >> 4))*NPTS + n)*16 + (ol & 15)] = bv;
        } else {
          int d = (Mblk - 2)*128 + ol;
          int p = (n & ~31) | (n & 3) | (((n >> 4) & 1) << 2) | (((n >> 2) & 3) << 3);
          vb[((size_t)b*DH + d)*NPTS + p] = bv;
        }
      }
    }
  }
}

// ---------------------------------------------------------------------------
// K2: depthwise 3x3x3 conv + scale/bias, x0.25 folded, bf16 in/out.
// ---------------------------------------------------------------------------
__global__ __launch_bounds__(512) void k_dw(
    const u16* __restrict__ qfb, const float* __restrict__ dww,
    const float* __restrict__ dws, const float* __restrict__ dwb,
    u16* __restrict__ qb)
{
  const int bc = blockIdx.x;            // b*128 + ch
  const int b  = bc >> 7;
  const int ch = bc & 127;
  const int n  = threadIdx.x;
  const int z = n >> 6, y = (n >> 3) & 7, xx = n & 7;
  float wv[27];
  #pragma unroll
  for (int i = 0; i < 27; i++) wv[i] = dww[ch*27 + i];
  const u16* qp = qfb + (size_t)bc * NPTS;
  float acc = 0.f;
  #pragma unroll
  for (int dz = 0; dz < 3; dz++){
    int zz = z + dz - 1; if ((unsigned)zz > 7u) continue;
    #pragma unroll
    for (int dy = 0; dy < 3; dy++){
      int yy = y + dy - 1; if ((unsigned)yy > 7u) continue;
      #pragma unroll
      for (int dx = 0; dx < 3; dx++){
        int xw = xx + dx - 1; if ((unsigned)xw > 7u) continue;
        acc += bf2f(qp[zz*64 + yy*8 + xw]) * wv[dz*9 + dy*3 + dx];
      }
    }
  }
  acc = (acc * dws[ch] + dwb[ch]) * 0.25f;   // fold 1/sqrt(KD)
  int hh = ch >> 4, cc = ch & 15;
  qb[(((size_t)b*NH + hh)*NPTS + n)*16 + cc] = (u16)f2bf_bits(acc);
}

// ---------------------------------------------------------------------------
// K_bias: bf16 bias table in TRANSPOSED-score C-layout:
// biasb[h][mtg 32][ntile 32][lane 64][r 4] u16, value = bias(m,n) with
// m = mtg*16 + (lane>>4)*4 + r, n = ntile*16 + (lane&15).
// ---------------------------------------------------------------------------
__global__ __launch_bounds__(256) void k_bias(
    const float* __restrict__ ab, const int* __restrict__ bidx,
    u32* __restrict__ biasb)
{
  const int blk = blockIdx.x;
  const int mtg = blk >> 5, ntile = blk & 31;
  const int lane = threadIdx.x & 63;
  const int h0 = threadIdx.x >> 6;
  const int qq = lane >> 4;
  const int n = ntile*16 + (lane & 15);
  int idx[4];
  #pragma unroll
  for (int r = 0; r < 4; r++)
    idx[r] = bidx[(size_t)n*NPTS + mtg*16 + qq*4 + r];
  for (int h = h0; h < NH; h += 4){
    float v0 = ab[h*NPTS + idx[0]], v1 = ab[h*NPTS + idx[1]];
    float v2 = ab[h*NPTS + idx[2]], v3 = ab[h*NPTS + idx[3]];
    u32* dst = biasb + (((size_t)(h*32 + mtg)*32 + ntile)*64 + lane)*2;
    dst[0] = pack2bf(v0, v1);
    dst[1] = pack2bf(v2, v3);
  }
}

// ---------------------------------------------------------------------------
// K3: LDS-free barrier-free MFMA flash attention, transposed scores,
// SOFTWARE-PIPELINED (one-window-ahead prefetch) with 2 n-tiles per wave.
// Grid (b*8+h, tg 0..3), block 256. Wave owns ntiles {tg*8+wave*2, +1}.
// Per 32-m window: 8 prefetched loads feed 12 MFMAs (4 score + 8 PV);
// aK and V fragments are shared across the two n-tiles.
// ---------------------------------------------------------------------------
__global__ __launch_bounds__(256, 4) void k_attn(
    const u16* __restrict__ qb, const u16* __restrict__ kb,
    const u16* __restrict__ vb, const u16* __restrict__ biasb,
    u16* __restrict__ attnout)
{
  const int hb = blockIdx.x, tg = blockIdx.y;
  const int b = hb >> 3, h = hb & 7;
  const int lane = threadIdx.x & 63, wave = threadIdx.x >> 6;
  const int c = lane & 15, q = lane >> 4;
  const int bh = b*NH + h;
  const int nt0 = tg*8 + wave*2;        // ntiles {nt0, nt0+1}
  const int n0 = nt0*16;

  const bf16x8 zfrag = {0,0,0,0,0,0,0,0};
  bf16x8 bQ0 = zfrag, bQ1 = zfrag;
  if (q < 2){
    bQ0 = *(const bf16x8*)(qb + (((size_t)bh*NPTS + n0 + c) << 4) + q*8);
    bQ1 = *(const bf16x8*)(qb + (((size_t)bh*NPTS + n0 + 16 + c) << 4) + q*8);
  }

  const u16* kbh = kb + ((size_t)bh*NPTS)*16;
  const u16* vbh = vb + ((size_t)b*DH + h*DHEAD)*NPTS;
  const u16* bw0 = biasb + (size_t)h*262144 + (size_t)nt0*256 + lane*4;

  f32x4 O0[4] = {{0,0,0,0},{0,0,0,0},{0,0,0,0},{0,0,0,0}};
  f32x4 O1[4] = {{0,0,0,0},{0,0,0,0},{0,0,0,0},{0,0,0,0}};
  float ls0 = 0.f, ls1 = 0.f;

  // pipeline registers (current window)
  bf16x8 aK0, aK1, V0, V1, V2, V3;
  uint2 u00, u01, u10, u11;

  auto loadw = [&](int win, bf16x8& k0, bf16x8& k1,
                   uint2& x00, uint2& x01, uint2& x10, uint2& x11,
                   bf16x8& v0, bf16x8& v1, bf16x8& v2, bf16x8& v3){
    const int mtg = win*2;
    if (q < 2){
      k0 = *(const bf16x8*)(kbh + (((size_t)(mtg*16 + c)) << 4) + q*8);
      k1 = *(const bf16x8*)(kbh + (((size_t)(mtg*16 + 16 + c)) << 4) + q*8);
    } else { k0 = zfrag; k1 = zfrag; }
    x00 = *(const uint2*)(bw0 + (size_t)mtg*8192);
    x01 = *(const uint2*)(bw0 + (size_t)(mtg+1)*8192);
    x10 = *(const uint2*)(bw0 + 256 + (size_t)mtg*8192);
    x11 = *(const uint2*)(bw0 + 256 + (size_t)(mtg+1)*8192);
    const int mv = win*32 + q*8;
    v0 = *(const bf16x8*)(vbh + (size_t)( 0 + c)*NPTS + mv);
    v1 = *(const bf16x8*)(vbh + (size_t)(16 + c)*NPTS + mv);
    v2 = *(const bf16x8*)(vbh + (size_t)(32 + c)*NPTS + mv);
    v3 = *(const bf16x8*)(vbh + (size_t)(48 + c)*NPTS + mv);
  };

  loadw(0, aK0, aK1, u00, u01, u10, u11, V0, V1, V2, V3);

  #pragma unroll
  for (int win = 0; win < 16; win++){
    // prefetch next window while computing this one
    bf16x8 nK0, nK1, nV0, nV1, nV2, nV3;
    uint2 m00, m01, m10, m11;
    if (win < 15)
      loadw(win+1, nK0, nK1, m00, m01, m10, m11, nV0, nV1, nV2, nV3);

    // ---- scores: 2 m-tiles x 2 n-tiles ----
    f32x4 c00, c01, c10, c11;
    c00[0]=bflo(u00.x); c00[1]=bfhi(u00.x); c00[2]=bflo(u00.y); c00[3]=bfhi(u00.y);
    c01[0]=bflo(u01.x); c01[1]=bfhi(u01.x); c01[2]=bflo(u01.y); c01[3]=bfhi(u01.y);
    c10[0]=bflo(u10.x); c10[1]=bfhi(u10.x); c10[2]=bflo(u10.y); c10[3]=bfhi(u10.y);
    c11[0]=bflo(u11.x); c11[1]=bfhi(u11.x); c11[2]=bflo(u11.y); c11[3]=bfhi(u11.y);
    f32x4 S00 = __builtin_amdgcn_mfma_f32_16x16x32_bf16(aK0, bQ0, c00, 0, 0, 0);
    f32x4 S01 = __builtin_amdgcn_mfma_f32_16x16x32_bf16(aK1, bQ0, c01, 0, 0, 0);
    f32x4 S10 = __builtin_amdgcn_mfma_f32_16x16x32_bf16(aK0, bQ1, c10, 0, 0, 0);
    f32x4 S11 = __builtin_amdgcn_mfma_f32_16x16x32_bf16(aK1, bQ1, c11, 0, 0, 0);

    // ---- exp + pack into PV A-fragments ----
    float e0, e1, e2, e3;
    B8 aP0, aP1;
    e0 = __expf(S00[0]); e1 = __expf(S00[1]); e2 = __expf(S00[2]); e3 = __expf(S00[3]);
    ls0 += (e0 + e1) + (e2 + e3);
    aP0.u4.x = pack2bf(e0, e1); aP0.u4.y = pack2bf(e2, e3);
    e0 = __expf(S01[0]); e1 = __expf(S01[1]); e2 = __expf(S01[2]); e3 = __expf(S01[3]);
    ls0 += (e0 + e1) + (e2 + e3);
    aP0.u4.z = pack2bf(e0, e1); aP0.u4.w = pack2bf(e2, e3);
    e0 = __expf(S10[0]); e1 = __expf(S10[1]); e2 = __expf(S10[2]); e3 = __expf(S10[3]);
    ls1 += (e0 + e1) + (e2 + e3);
    aP1.u4.x = pack2bf(e0, e1); aP1.u4.y = pack2bf(e2, e3);
    e0 = __expf(S11[0]); e1 = __expf(S11[1]); e2 = __expf(S11[2]); e3 = __expf(S11[3]);
    ls1 += (e0 + e1) + (e2 + e3);
    aP1.u4.z = pack2bf(e0, e1); aP1.u4.w = pack2bf(e2, e3);

    // ---- PV: 4 d-tiles x 2 n-tiles, V shared ----
    O0[0] = __builtin_amdgcn_mfma_f32_16x16x32_bf16(aP0.v, V0, O0[0], 0, 0, 0);
    O1[0] = __builtin_amdgcn_mfma_f32_16x16x32_bf16(aP1.v, V0, O1[0], 0, 0, 0);
    O0[1] = __builtin_amdgcn_mfma_f32_16x16x32_bf16(aP0.v, V1, O0[1], 0, 0, 0);
    O1[1] = __builtin_amdgcn_mfma_f32_16x16x32_bf16(aP1.v, V1, O1[1], 0, 0, 0);
    O0[2] = __builtin_amdgcn_mfma_f32_16x16x32_bf16(aP0.v, V2, O0[2], 0, 0, 0);
    O1[2] = __builtin_amdgcn_mfma_f32_16x16x32_bf16(aP1.v, V2, O1[2], 0, 0, 0);
    O0[3] = __builtin_amdgcn_mfma_f32_16x16x32_bf16(aP0.v, V3, O0[3], 0, 0, 0);
    O1[3] = __builtin_amdgcn_mfma_f32_16x16x32_bf16(aP1.v, V3, O1[3], 0, 0, 0);

    // rotate pipeline
    if (win < 15){
      aK0 = nK0; aK1 = nK1;
      u00 = m00; u01 = m01; u10 = m10; u11 = m11;
      V0 = nV0; V1 = nV1; V2 = nV2; V3 = nV3;
    }
  }

  // ---- l reduction over the 4 m-quads ----
  ls0 += __shfl_xor(ls0, 16, 64);
  ls0 += __shfl_xor(ls0, 32, 64);
  ls1 += __shfl_xor(ls1, 16, 64);
  ls1 += __shfl_xor(ls1, 32, 64);
  f32x4 inv0, inv1;
  #pragma unroll
  for (int r = 0; r < 4; r++){
    inv0[r] = 1.0f / __shfl(ls0, q*4 + r, 64);
    inv1[r] = 1.0f / __shfl(ls1, q*4 + r, 64);
  }

  // ---- epilogue: relu(O/l) -> attn[b][n][dh] bf16 ----
  u16* ao = attnout + ((size_t)(b*NPTS + n0))*DH + h*DHEAD;
  #pragma unroll
  for (int dt = 0; dt < 4; dt++)
    #pragma unroll
    for (int r = 0; r < 4; r++){
      ao[(size_t)(q*4 + r)*DH + dt*16 + c] =
          (u16)f2bf_bits(fmaxf(O0[dt][r]*inv0[r], 0.f));
      ao[(size_t)(16 + q*4 + r)*DH + dt*16 + c] =
          (u16)f2bf_bits(fmaxf(O1[dt][r]*inv1[r], 0.f));
    }
}

// ---------------------------------------------------------------------------
// K4: proj MFMA GEMM (unchanged).
// ---------------------------------------------------------------------------
__global__ __launch_bounds__(256) void k_proj(
    const u16* __restrict__ attn, const u16* __restrict__ pwb,
    const float* __restrict__ bias, float* __restrict__ out)
{
  const int Mblk = blockIdx.x, Nblk = blockIdx.y, b = blockIdx.z;
  const int tid = threadIdx.x, wave = tid >> 6, lane = tid & 63;
  const int wm = wave >> 1, wn = wave & 1;
  const int c = lane & 15, q = lane >> 4;
  const int Mbase = Mblk*128 + wm*64;
  const int Nbase = Nblk*128 + wn*64;

  f32x4 acc[4][4];
  #pragma unroll
  for (int mt = 0; mt < 4; mt++){
    f32x4 bi;
    #pragma unroll
    for (int r = 0; r < 4; r++) bi[r] = bias[Mbase + mt*16 + q*4 + r];
    #pragma unroll
    for (int nt = 0; nt < 4; nt++) acc[mt][nt] = bi;
  }

  const u16* arow = attn + (size_t)b*NPTS*DH;

  for (int kc8 = 0; kc8 < 16; kc8++){
    const int kc = kc8*32;
    bf16x8 aW[4], bA[4];
    #pragma unroll
    for (int mt = 0; mt < 4; mt++)
      aW[mt] = *(const bf16x8*)(pwb + (size_t)(Mbase + mt*16 + c)*DH + kc + q*8);
    #pragma unroll
    for (int nt = 0; nt < 4; nt++)
      bA[nt] = *(const bf16x8*)(arow + (size_t)(Nbase + nt*16 + c)*DH + kc + q*8);
    #pragma unroll
    for (int mt = 0; mt < 4; mt++)
      #pragma unroll
      for (int nt = 0; nt < 4; nt++)
        acc[mt][nt] = __builtin_amdgcn_mfma_f32_16x16x32_bf16(
            aW[mt], bA[nt], acc[mt][nt], 0, 0, 0);
  }

  #pragma unroll
  for (int mt = 0; mt < 4; mt++){
    #pragma unroll
    for (int nt = 0; nt < 4; nt++){
      const int n = Nbase + nt*16 + c;
      #pragma unroll
      for (int r = 0; r < 4; r++){
        int o = Mbase + mt*16 + q*4 + r;
        out[((size_t)b*DIM + o)*NPTS + n] = acc[mt][nt][r];
      }
    }
  }
}

// ---------------------------------------------------------------------------
extern "C" void kernel_launch(void* const* d_in, const int* in_sizes, int n_in,
                              void* d_out, int out_size, void* d_ws, size_t ws_size,
                              hipStream_t stream)
{
  const float* x     = (const float*)d_in[0];
  const float* qkv_w = (const float*)d_in[1];
  const float* qkv_s = (const float*)d_in[2];
  const float* qkv_b = (const float*)d_in[3];
  const float* dw_w  = (const float*)d_in[4];
  const float* dw_s  = (const float*)d_in[5];
  const float* dw_b  = (const float*)d_in[6];
  const float* ab    = (const float*)d_in[7];
  const float* pw    = (const float*)d_in[8];
  const float* ps    = (const float*)d_in[9];
  const float* pb    = (const float*)d_in[10];
  const int* bidx    = (const int*)d_in[11];

  char* ws = (char*)d_ws;
  u16*   qfb   = (u16*)  (ws);                  //  4 MB (B,128,512) bf16
  u16*   qb    = (u16*)  (ws + ( 4u << 20));    //  4 MB (B,8,512,16) bf16
  u16*   kb    = (u16*)  (ws + ( 8u << 20));    //  4 MB (B,8,512,16) bf16
  u16*   vb    = (u16*)  (ws + (12u << 20));    // 16 MB (B,512,512) bf16 [b][d][p]
  u16*   attn  = (u16*)  (ws + (28u << 20));    // 16 MB (B,512,512) bf16 rows [n][dh]
  u32*   biasb = (u32*)  (ws + (44u << 20));    //  4 MB (8,32,32,64,4) bf16 S^T layout
  u32*   wqb   = (u32*)  (ws + (48u << 20));    // 384 KB (768,256) bf16
  u32*   pwb   = (u32*)  (ws + (49u << 20));    // 256 KB (256,512) bf16

  k_prep<<<dim3(640),      256, 0, stream>>>(qkv_w, qkv_s, pw, ps, wqb, pwb);
  k_qkv <<<dim3(6, 4, 32), 256, 0, stream>>>(x, (const u16*)wqb, qkv_b, qfb, kb, vb);
  k_dw  <<<dim3(32*128),   512, 0, stream>>>(qfb, dw_w, dw_s, dw_b, qb);
  k_bias<<<dim3(1024),     256, 0, stream>>>(ab, bidx, biasb);
  k_attn<<<dim3(256, 4),   256, 0, stream>>>(qb, kb, vb, (const u16*)biasb, attn);
  k_proj<<<dim3(2, 4, 32), 256, 0, stream>>>(attn, (const u16*)pwb, pb, (float*)d_out);
}

// Round 9
// 283.439 us; speedup vs baseline: 1.2240x; 1.2240x over previous
//
#include <hip/hip_runtime.h>

typedef unsigned int u32;
typedef unsigned short u16;
typedef __attribute__((ext_vector_type(8))) short bf16x8;
typedef __attribute__((ext_vector_type(4))) float f32x4;

constexpr int BATCH = 32;
constexpr int DIM   = 256;
constexpr int NPTS  = 512;
constexpr int NH    = 8;
constexpr int KD    = 16;
constexpr int DHEAD = 64;
constexpr int NH_KD = 128;
constexpr int DH    = 512;

__device__ __forceinline__ float bflo(u32 u){ return __uint_as_float(u << 16); }
__device__ __forceinline__ float bfhi(u32 u){ return __uint_as_float(u & 0xffff0000u); }
__device__ __forceinline__ float bf2f(u16 u){ return __uint_as_float(((u32)u) << 16); }
__device__ __forceinline__ u32 f2bf_bits(float f){
  u32 u = __float_as_uint(f);
  return (u + 0x7fffu + ((u >> 16) & 1u)) >> 16;
}
__device__ __forceinline__ u32 pack2bf(float a, float b){
  return f2bf_bits(a) | (f2bf_bits(b) << 16);
}

union B8 { bf16x8 v; uint2 u2[2]; uint4 u4; };

// ---------------------------------------------------------------------------
// K0: fold scale into weights, convert to bf16.
// ---------------------------------------------------------------------------
__global__ __launch_bounds__(256) void k_prep(
    const float* __restrict__ wq, const float* __restrict__ sq,
    const float* __restrict__ wp, const float* __restrict__ sp,
    u32* __restrict__ wqb, u32* __restrict__ pwb)
{
  int t = blockIdx.x * 256 + threadIdx.x;
  if (t < 98304){                      // 768*256/2
    int i = 2*t;
    float s = sq[i >> 8];
    wqb[t] = pack2bf(wq[i]*s, wq[i+1]*s);
  } else {
    int j = t - 98304;                 // 256*512/2
    int i = 2*j;
    float s = sp[i >> 9];
    pwb[j] = pack2bf(wp[i]*s, wp[i+1]*s);
  }
}

// ---------------------------------------------------------------------------
// K1: qkv MFMA GEMM. C[o 768][n 512] per batch, K=256.
// v stored with m-columns permuted within 32-blocks so k_attn's transposed
// score registers directly form the PV A-fragment:
//   p = (n&~31) | (n&3) | (((n>>4)&1)<<2) | (((n>>2)&3)<<3)
// ---------------------------------------------------------------------------
__global__ __launch_bounds__(256) void k_qkv(
    const float* __restrict__ x, const u16* __restrict__ wqb,
    const float* __restrict__ bias,
    u16* __restrict__ qfb, u16* __restrict__ kb, u16* __restrict__ vb)
{
  __shared__ __align__(16) u16 Xl[128*36];

  const int Mblk = blockIdx.x, Nblk = blockIdx.y, b = blockIdx.z;
  const int tid = threadIdx.x, wave = tid >> 6, lane = tid & 63;
  const int wm = wave >> 1, wn = wave & 1;
  const int c = lane & 15, q = lane >> 4;
  const int Mbase = Mblk*128 + wm*64;

  f32x4 acc[4][4];
  #pragma unroll
  for (int mt = 0; mt < 4; mt++){
    f32x4 bi;
    #pragma unroll
    for (int r = 0; r < 4; r++) bi[r] = bias[Mbase + mt*16 + q*4 + r];
    #pragma unroll
    for (int nt = 0; nt < 4; nt++) acc[mt][nt] = bi;
  }

  const float* xb = x + (size_t)b*DIM*NPTS + Nblk*128;

  for (int kc8 = 0; kc8 < 8; kc8++){
    const int kc = kc8*32;
    __syncthreads();
    #pragma unroll
    for (int it = 0; it < 4; it++){
      int n2 = 2*((tid & 31) + 32*(it & 1));
      int cc = 2*((tid >> 5) + 8*(it >> 1));
      const float* xr = xb + (size_t)(kc + cc)*NPTS + n2;
      float2 A = *(const float2*)xr;
      float2 Bv = *(const float2*)(xr + NPTS);
      *(u32*)(Xl + (size_t)n2*36 + cc)     = pack2bf(A.x, Bv.x);
      *(u32*)(Xl + (size_t)(n2+1)*36 + cc) = pack2bf(A.y, Bv.y);
    }
    __syncthreads();

    bf16x8 aW[4];
    #pragma unroll
    for (int mt = 0; mt < 4; mt++)
      aW[mt] = *(const bf16x8*)(wqb + (size_t)(Mbase + mt*16 + c)*256 + kc + q*8);
    B8 bX[4];
    #pragma unroll
    for (int nt = 0; nt < 4; nt++){
      const u16* base = Xl + (size_t)(wn*64 + nt*16 + c)*36 + q*8;
      bX[nt].u2[0] = *(const uint2*)(base);
      bX[nt].u2[1] = *(const uint2*)(base + 4);
    }
    #pragma unroll
    for (int mt = 0; mt < 4; mt++)
      #pragma unroll
      for (int nt = 0; nt < 4; nt++)
        acc[mt][nt] = __builtin_amdgcn_mfma_f32_16x16x32_bf16(
            aW[mt], bX[nt].v, acc[mt][nt], 0, 0, 0);
  }

  #pragma unroll
  for (int mt = 0; mt < 4; mt++){
    const int ob = wm*64 + mt*16 + q*4;
    #pragma unroll
    for (int nt = 0; nt < 4; nt++){
      const int n = Nblk*128 + wn*64 + nt*16 + c;
      #pragma unroll
      for (int r = 0; r < 4; r++){
        u16 bv = (u16)f2bf_bits(acc[mt][nt][r]);
        int ol = ob + r;
        if (Mblk == 0){
          qfb[((size_t)b*NH_KD + ol)*NPTS + n] = bv;
        } else if (Mblk == 1){
          kb[(((size_t)b*NH + (ol >> 4))*NPTS + n)*16 + (ol & 15)] = bv;
        } else {
          int d = (Mblk - 2)*128 + ol;
          int p = (n & ~31) | (n & 3) | (((n >> 4) & 1) << 2) | (((n >> 2) & 3) << 3);
          vb[((size_t)b*DH + d)*NPTS + p] = bv;
        }
      }
    }
  }
}

// ---------------------------------------------------------------------------
// K2: depthwise 3x3x3 conv + scale/bias, x0.25 folded, bf16 in/out.
// ---------------------------------------------------------------------------
__global__ __launch_bounds__(512) void k_dw(
    const u16* __restrict__ qfb, const float* __restrict__ dww,
    const float* __restrict__ dws, const float* __restrict__ dwb,
    u16* __restrict__ qb)
{
  const int bc = blockIdx.x;            // b*128 + ch
  const int b  = bc >> 7;
  const int ch = bc & 127;
  const int n  = threadIdx.x;
  const int z = n >> 6, y = (n >> 3) & 7, xx = n & 7;
  float wv[27];
  #pragma unroll
  for (int i = 0; i < 27; i++) wv[i] = dww[ch*27 + i];
  const u16* qp = qfb + (size_t)bc * NPTS;
  float acc = 0.f;
  #pragma unroll
  for (int dz = 0; dz < 3; dz++){
    int zz = z + dz - 1; if ((unsigned)zz > 7u) continue;
    #pragma unroll
    for (int dy = 0; dy < 3; dy++){
      int yy = y + dy - 1; if ((unsigned)yy > 7u) continue;
      #pragma unroll
      for (int dx = 0; dx < 3; dx++){
        int xw = xx + dx - 1; if ((unsigned)xw > 7u) continue;
        acc += bf2f(qp[zz*64 + yy*8 + xw]) * wv[dz*9 + dy*3 + dx];
      }
    }
  }
  acc = (acc * dws[ch] + dwb[ch]) * 0.25f;   // fold 1/sqrt(KD)
  int hh = ch >> 4, cc = ch & 15;
  qb[(((size_t)b*NH + hh)*NPTS + n)*16 + cc] = (u16)f2bf_bits(acc);
}

// ---------------------------------------------------------------------------
// K_bias: bf16 bias table in TRANSPOSED-score C-layout:
// biasb[h][mtg 32][ntile 32][lane 64][r 4] u16, value = bias(m,n) with
// m = mtg*16 + (lane>>4)*4 + r, n = ntile*16 + (lane&15).
// ---------------------------------------------------------------------------
__global__ __launch_bounds__(256) void k_bias(
    const float* __restrict__ ab, const int* __restrict__ bidx,
    u32* __restrict__ biasb)
{
  const int blk = blockIdx.x;
  const int mtg = blk >> 5, ntile = blk & 31;
  const int lane = threadIdx.x & 63;
  const int h0 = threadIdx.x >> 6;
  const int qq = lane >> 4;
  const int n = ntile*16 + (lane & 15);
  int idx[4];
  #pragma unroll
  for (int r = 0; r < 4; r++)
    idx[r] = bidx[(size_t)n*NPTS + mtg*16 + qq*4 + r];
  for (int h = h0; h < NH; h += 4){
    float v0 = ab[h*NPTS + idx[0]], v1 = ab[h*NPTS + idx[1]];
    float v2 = ab[h*NPTS + idx[2]], v3 = ab[h*NPTS + idx[3]];
    u32* dst = biasb + (((size_t)(h*32 + mtg)*32 + ntile)*64 + lane)*2;
    dst[0] = pack2bf(v0, v1);
    dst[1] = pack2bf(v2, v3);
  }
}

// ---------------------------------------------------------------------------
// K3: LDS-free barrier-free MFMA flash attention, transposed scores.
// 2 n-tiles per wave (V frags shared). Software pipeline prefetches ONLY
// aK + bias (24 rotation regs); V loads issue at the top of each window and
// their L2 latency is covered by the score-MFMA + exp/pack chain.
// launch_bounds(256,3): reg cap ~170 for ~125 live -> no spill (R6/R8 lesson:
// spill shows as WRITE_SIZE blowup; must stay ~16 MB).
// ---------------------------------------------------------------------------
__global__ __launch_bounds__(256, 3) void k_attn(
    const u16* __restrict__ qb, const u16* __restrict__ kb,
    const u16* __restrict__ vb, const u16* __restrict__ biasb,
    u16* __restrict__ attnout)
{
  const int hb = blockIdx.x, tg = blockIdx.y;
  const int b = hb >> 3, h = hb & 7;
  const int lane = threadIdx.x & 63, wave = threadIdx.x >> 6;
  const int c = lane & 15, q = lane >> 4;
  const int bh = b*NH + h;
  const int nt0 = tg*8 + wave*2;        // ntiles {nt0, nt0+1}
  const int n0 = nt0*16;

  const bf16x8 zfrag = {0,0,0,0,0,0,0,0};
  bf16x8 bQ0 = zfrag, bQ1 = zfrag;
  if (q < 2){
    bQ0 = *(const bf16x8*)(qb + (((size_t)bh*NPTS + n0 + c) << 4) + q*8);
    bQ1 = *(const bf16x8*)(qb + (((size_t)bh*NPTS + n0 + 16 + c) << 4) + q*8);
  }

  const u16* kbh = kb + ((size_t)bh*NPTS)*16;
  const u16* vbh = vb + ((size_t)b*DH + h*DHEAD)*NPTS;
  const u16* bw0 = biasb + (size_t)h*262144 + (size_t)nt0*256 + lane*4;

  f32x4 O0[4] = {{0,0,0,0},{0,0,0,0},{0,0,0,0},{0,0,0,0}};
  f32x4 O1[4] = {{0,0,0,0},{0,0,0,0},{0,0,0,0},{0,0,0,0}};
  float ls0 = 0.f, ls1 = 0.f;

  // rotation registers: current window's aK + bias only (small!)
  bf16x8 aK0, aK1;
  uint2 u00, u01, u10, u11;

  auto loadKB = [&](int win, bf16x8& k0, bf16x8& k1,
                    uint2& x00, uint2& x01, uint2& x10, uint2& x11){
    const int mtg = win*2;
    if (q < 2){
      k0 = *(const bf16x8*)(kbh + (((size_t)(mtg*16 + c)) << 4) + q*8);
      k1 = *(const bf16x8*)(kbh + (((size_t)(mtg*16 + 16 + c)) << 4) + q*8);
    } else { k0 = zfrag; k1 = zfrag; }
    x00 = *(const uint2*)(bw0 + (size_t)mtg*8192);
    x01 = *(const uint2*)(bw0 + (size_t)(mtg+1)*8192);
    x10 = *(const uint2*)(bw0 + 256 + (size_t)mtg*8192);
    x11 = *(const uint2*)(bw0 + 256 + (size_t)(mtg+1)*8192);
  };

  loadKB(0, aK0, aK1, u00, u01, u10, u11);

  #pragma unroll
  for (int win = 0; win < 16; win++){
    // ---- V loads for THIS window issue first (latency covered below) ----
    const int mv = win*32 + q*8;
    bf16x8 V0 = *(const bf16x8*)(vbh + (size_t)( 0 + c)*NPTS + mv);
    bf16x8 V1 = *(const bf16x8*)(vbh + (size_t)(16 + c)*NPTS + mv);
    bf16x8 V2 = *(const bf16x8*)(vbh + (size_t)(32 + c)*NPTS + mv);
    bf16x8 V3 = *(const bf16x8*)(vbh + (size_t)(48 + c)*NPTS + mv);

    // ---- prefetch next window's aK/bias (small rotation state) ----
    bf16x8 nK0, nK1;
    uint2 m00, m01, m10, m11;
    if (win < 15)
      loadKB(win+1, nK0, nK1, m00, m01, m10, m11);

    // ---- scores: 2 m-tiles x 2 n-tiles ----
    f32x4 c00, c01, c10, c11;
    c00[0]=bflo(u00.x); c00[1]=bfhi(u00.x); c00[2]=bflo(u00.y); c00[3]=bfhi(u00.y);
    c01[0]=bflo(u01.x); c01[1]=bfhi(u01.x); c01[2]=bflo(u01.y); c01[3]=bfhi(u01.y);
    c10[0]=bflo(u10.x); c10[1]=bfhi(u10.x); c10[2]=bflo(u10.y); c10[3]=bfhi(u10.y);
    c11[0]=bflo(u11.x); c11[1]=bfhi(u11.x); c11[2]=bflo(u11.y); c11[3]=bfhi(u11.y);
    f32x4 S00 = __builtin_amdgcn_mfma_f32_16x16x32_bf16(aK0, bQ0, c00, 0, 0, 0);
    f32x4 S01 = __builtin_amdgcn_mfma_f32_16x16x32_bf16(aK1, bQ0, c01, 0, 0, 0);
    f32x4 S10 = __builtin_amdgcn_mfma_f32_16x16x32_bf16(aK0, bQ1, c10, 0, 0, 0);
    f32x4 S11 = __builtin_amdgcn_mfma_f32_16x16x32_bf16(aK1, bQ1, c11, 0, 0, 0);

    // ---- exp + pack into PV A-fragments ----
    float e0, e1, e2, e3;
    B8 aP0, aP1;
    e0 = __expf(S00[0]); e1 = __expf(S00[1]); e2 = __expf(S00[2]); e3 = __expf(S00[3]);
    ls0 += (e0 + e1) + (e2 + e3);
    aP0.u4.x = pack2bf(e0, e1); aP0.u4.y = pack2bf(e2, e3);
    e0 = __expf(S01[0]); e1 = __expf(S01[1]); e2 = __expf(S01[2]); e3 = __expf(S01[3]);
    ls0 += (e0 + e1) + (e2 + e3);
    aP0.u4.z = pack2bf(e0, e1); aP0.u4.w = pack2bf(e2, e3);
    e0 = __expf(S10[0]); e1 = __expf(S10[1]); e2 = __expf(S10[2]); e3 = __expf(S10[3]);
    ls1 += (e0 + e1) + (e2 + e3);
    aP1.u4.x = pack2bf(e0, e1); aP1.u4.y = pack2bf(e2, e3);
    e0 = __expf(S11[0]); e1 = __expf(S11[1]); e2 = __expf(S11[2]); e3 = __expf(S11[3]);
    ls1 += (e0 + e1) + (e2 + e3);
    aP1.u4.z = pack2bf(e0, e1); aP1.u4.w = pack2bf(e2, e3);

    // ---- PV: 4 d-tiles x 2 n-tiles, V shared ----
    O0[0] = __builtin_amdgcn_mfma_f32_16x16x32_bf16(aP0.v, V0, O0[0], 0, 0, 0);
    O1[0] = __builtin_amdgcn_mfma_f32_16x16x32_bf16(aP1.v, V0, O1[0], 0, 0, 0);
    O0[1] = __builtin_amdgcn_mfma_f32_16x16x32_bf16(aP0.v, V1, O0[1], 0, 0, 0);
    O1[1] = __builtin_amdgcn_mfma_f32_16x16x32_bf16(aP1.v, V1, O1[1], 0, 0, 0);
    O0[2] = __builtin_amdgcn_mfma_f32_16x16x32_bf16(aP0.v, V2, O0[2], 0, 0, 0);
    O1[2] = __builtin_amdgcn_mfma_f32_16x16x32_bf16(aP1.v, V2, O1[2], 0, 0, 0);
    O0[3] = __builtin_amdgcn_mfma_f32_16x16x32_bf16(aP0.v, V3, O0[3], 0, 0, 0);
    O1[3] = __builtin_amdgcn_mfma_f32_16x16x32_bf16(aP1.v, V3, O1[3], 0, 0, 0);

    // rotate
    if (win < 15){
      aK0 = nK0; aK1 = nK1;
      u00 = m00; u01 = m01; u10 = m10; u11 = m11;
    }
  }

  // ---- l reduction over the 4 m-quads ----
  ls0 += __shfl_xor(ls0, 16, 64);
  ls0 += __shfl_xor(ls0, 32, 64);
  ls1 += __shfl_xor(ls1, 16, 64);
  ls1 += __shfl_xor(ls1, 32, 64);
  f32x4 inv0, inv1;
  #pragma unroll
  for (int r = 0; r < 4; r++){
    inv0[r] = 1.0f / __shfl(ls0, q*4 + r, 64);
    inv1[r] = 1.0f / __shfl(ls1, q*4 + r, 64);
  }

  // ---- epilogue: relu(O/l) -> attn[b][n][dh] bf16 ----
  u16* ao = attnout + ((size_t)(b*NPTS + n0))*DH + h*DHEAD;
  #pragma unroll
  for (int dt = 0; dt < 4; dt++)
    #pragma unroll
    for (int r = 0; r < 4; r++){
      ao[(size_t)(q*4 + r)*DH + dt*16 + c] =
          (u16)f2bf_bits(fmaxf(O0[dt][r]*inv0[r], 0.f));
      ao[(size_t)(16 + q*4 + r)*DH + dt*16 + c] =
          (u16)f2bf_bits(fmaxf(O1[dt][r]*inv1[r], 0.f));
    }
}

// ---------------------------------------------------------------------------
// K4: proj MFMA GEMM (unchanged).
// ---------------------------------------------------------------------------
__global__ __launch_bounds__(256) void k_proj(
    const u16* __restrict__ attn, const u16* __restrict__ pwb,
    const float* __restrict__ bias, float* __restrict__ out)
{
  const int Mblk = blockIdx.x, Nblk = blockIdx.y, b = blockIdx.z;
  const int tid = threadIdx.x, wave = tid >> 6, lane = tid & 63;
  const int wm = wave >> 1, wn = wave & 1;
  const int c = lane & 15, q = lane >> 4;
  const int Mbase = Mblk*128 + wm*64;
  const int Nbase = Nblk*128 + wn*64;

  f32x4 acc[4][4];
  #pragma unroll
  for (int mt = 0; mt < 4; mt++){
    f32x4 bi;
    #pragma unroll
    for (int r = 0; r < 4; r++) bi[r] = bias[Mbase + mt*16 + q*4 + r];
    #pragma unroll
    for (int nt = 0; nt < 4; nt++) acc[mt][nt] = bi;
  }

  const u16* arow = attn + (size_t)b*NPTS*DH;

  for (int kc8 = 0; kc8 < 16; kc8++){
    const int kc = kc8*32;
    bf16x8 aW[4], bA[4];
    #pragma unroll
    for (int mt = 0; mt < 4; mt++)
      aW[mt] = *(const bf16x8*)(pwb + (size_t)(Mbase + mt*16 + c)*DH + kc + q*8);
    #pragma unroll
    for (int nt = 0; nt < 4; nt++)
      bA[nt] = *(const bf16x8*)(arow + (size_t)(Nbase + nt*16 + c)*DH + kc + q*8);
    #pragma unroll
    for (int mt = 0; mt < 4; mt++)
      #pragma unroll
      for (int nt = 0; nt < 4; nt++)
        acc[mt][nt] = __builtin_amdgcn_mfma_f32_16x16x32_bf16(
            aW[mt], bA[nt], acc[mt][nt], 0, 0, 0);
  }

  #pragma unroll
  for (int mt = 0; mt < 4; mt++){
    #pragma unroll
    for (int nt = 0; nt < 4; nt++){
      const int n = Nbase + nt*16 + c;
      #pragma unroll
      for (int r = 0; r < 4; r++){
        int o = Mbase + mt*16 + q*4 + r;
        out[((size_t)b*DIM + o)*NPTS + n] = acc[mt][nt][r];
      }
    }
  }
}

// ---------------------------------------------------------------------------
extern "C" void kernel_launch(void* const* d_in, const int* in_sizes, int n_in,
                              void* d_out, int out_size, void* d_ws, size_t ws_size,
                              hipStream_t stream)
{
  const float* x     = (const float*)d_in[0];
  const float* qkv_w = (const float*)d_in[1];
  const float* qkv_s = (const float*)d_in[2];
  const float* qkv_b = (const float*)d_in[3];
  const float* dw_w  = (const float*)d_in[4];
  const float* dw_s  = (const float*)d_in[5];
  const float* dw_b  = (const float*)d_in[6];
  const float* ab    = (const float*)d_in[7];
  const float* pw    = (const float*)d_in[8];
  const float* ps    = (const float*)d_in[9];
  const float* pb    = (const float*)d_in[10];
  const int* bidx    = (const int*)d_in[11];

  char* ws = (char*)d_ws;
  u16*   qfb   = (u16*)  (ws);                  //  4 MB (B,128,512) bf16
  u16*   qb    = (u16*)  (ws + ( 4u << 20));    //  4 MB (B,8,512,16) bf16
  u16*   kb    = (u16*)  (ws + ( 8u << 20));    //  4 MB (B,8,512,16) bf16
  u16*   vb    = (u16*)  (ws + (12u << 20));    // 16 MB (B,512,512) bf16 [b][d][p]
  u16*   attn  = (u16*)  (ws + (28u << 20));    // 16 MB (B,512,512) bf16 rows [n][dh]
  u32*   biasb = (u32*)  (ws + (44u << 20));    //  4 MB (8,32,32,64,4) bf16 S^T layout
  u32*   wqb   = (u32*)  (ws + (48u << 20));    // 384 KB (768,256) bf16
  u32*   pwb   = (u32*)  (ws + (49u << 20));    // 256 KB (256,512) bf16

  k_prep<<<dim3(640),      256, 0, stream>>>(qkv_w, qkv_s, pw, ps, wqb, pwb);
  k_qkv <<<dim3(6, 4, 32), 256, 0, stream>>>(x, (const u16*)wqb, qkv_b, qfb, kb, vb);
  k_dw  <<<dim3(32*128),   512, 0, stream>>>(qfb, dw_w, dw_s, dw_b, qb);
  k_bias<<<dim3(1024),     256, 0, stream>>>(ab, bidx, biasb);
  k_attn<<<dim3(256, 4),   256, 0, stream>>>(qb, kb, vb, (const u16*)biasb, attn);
  k_proj<<<dim3(2, 4, 32), 256, 0, stream>>>(attn, (const u16*)pwb, pb, (float*)d_out);
}

// Round 10
// 229.457 us; speedup vs baseline: 1.5120x; 1.2353x over previous
//
#include <hip/hip_runtime.h>

typedef unsigned int u32;
typedef unsigned short u16;
typedef __attribute__((ext_vector_type(8))) short bf16x8;
typedef __attribute__((ext_vector_type(4))) float f32x4;

constexpr int BATCH = 32;
constexpr int DIM   = 256;
constexpr int NPTS  = 512;
constexpr int NH    = 8;
constexpr int KD    = 16;
constexpr int DHEAD = 64;
constexpr int NH_KD = 128;
constexpr int DH    = 512;

__device__ __forceinline__ float bflo(u32 u){ return __uint_as_float(u << 16); }
__device__ __forceinline__ float bfhi(u32 u){ return __uint_as_float(u & 0xffff0000u); }
__device__ __forceinline__ float bf2f(u16 u){ return __uint_as_float(((u32)u) << 16); }
__device__ __forceinline__ u32 f2bf_bits(float f){
  u32 u = __float_as_uint(f);
  return (u + 0x7fffu + ((u >> 16) & 1u)) >> 16;
}
__device__ __forceinline__ u32 pack2bf(float a, float b){
  return f2bf_bits(a) | (f2bf_bits(b) << 16);
}

union B8 { bf16x8 v; uint2 u2[2]; uint4 u4; };

// ---------------------------------------------------------------------------
// K0: fold scale into weights, convert to bf16.
// ---------------------------------------------------------------------------
__global__ __launch_bounds__(256) void k_prep(
    const float* __restrict__ wq, const float* __restrict__ sq,
    const float* __restrict__ wp, const float* __restrict__ sp,
    u32* __restrict__ wqb, u32* __restrict__ pwb)
{
  int t = blockIdx.x * 256 + threadIdx.x;
  if (t < 98304){                      // 768*256/2
    int i = 2*t;
    float s = sq[i >> 8];
    wqb[t] = pack2bf(wq[i]*s, wq[i+1]*s);
  } else {
    int j = t - 98304;                 // 256*512/2
    int i = 2*j;
    float s = sp[i >> 9];
    pwb[j] = pack2bf(wp[i]*s, wp[i+1]*s);
  }
}

// ---------------------------------------------------------------------------
// K1: qkv MFMA GEMM. C[o 768][n 512] per batch, K=256.
// v stored with m-columns permuted within 32-blocks so k_attn's transposed
// score registers directly form the PV A-fragment:
//   p = (n&~31) | (n&3) | (((n>>4)&1)<<2) | (((n>>2)&3)<<3)
// ---------------------------------------------------------------------------
__global__ __launch_bounds__(256) void k_qkv(
    const float* __restrict__ x, const u16* __restrict__ wqb,
    const float* __restrict__ bias,
    u16* __restrict__ qfb, u16* __restrict__ kb, u16* __restrict__ vb)
{
  __shared__ __align__(16) u16 Xl[128*36];

  const int Mblk = blockIdx.x, Nblk = blockIdx.y, b = blockIdx.z;
  const int tid = threadIdx.x, wave = tid >> 6, lane = tid & 63;
  const int wm = wave >> 1, wn = wave & 1;
  const int c = lane & 15, q = lane >> 4;
  const int Mbase = Mblk*128 + wm*64;

  f32x4 acc[4][4];
  #pragma unroll
  for (int mt = 0; mt < 4; mt++){
    f32x4 bi;
    #pragma unroll
    for (int r = 0; r < 4; r++) bi[r] = bias[Mbase + mt*16 + q*4 + r];
    #pragma unroll
    for (int nt = 0; nt < 4; nt++) acc[mt][nt] = bi;
  }

  const float* xb = x + (size_t)b*DIM*NPTS + Nblk*128;

  for (int kc8 = 0; kc8 < 8; kc8++){
    const int kc = kc8*32;
    __syncthreads();
    #pragma unroll
    for (int it = 0; it < 4; it++){
      int n2 = 2*((tid & 31) + 32*(it & 1));
      int cc = 2*((tid >> 5) + 8*(it >> 1));
      const float* xr = xb + (size_t)(kc + cc)*NPTS + n2;
      float2 A = *(const float2*)xr;
      float2 Bv = *(const float2*)(xr + NPTS);
      *(u32*)(Xl + (size_t)n2*36 + cc)     = pack2bf(A.x, Bv.x);
      *(u32*)(Xl + (size_t)(n2+1)*36 + cc) = pack2bf(A.y, Bv.y);
    }
    __syncthreads();

    bf16x8 aW[4];
    #pragma unroll
    for (int mt = 0; mt < 4; mt++)
      aW[mt] = *(const bf16x8*)(wqb + (size_t)(Mbase + mt*16 + c)*256 + kc + q*8);
    B8 bX[4];
    #pragma unroll
    for (int nt = 0; nt < 4; nt++){
      const u16* base = Xl + (size_t)(wn*64 + nt*16 + c)*36 + q*8;
      bX[nt].u2[0] = *(const uint2*)(base);
      bX[nt].u2[1] = *(const uint2*)(base + 4);
    }
    #pragma unroll
    for (int mt = 0; mt < 4; mt++)
      #pragma unroll
      for (int nt = 0; nt < 4; nt++)
        acc[mt][nt] = __builtin_amdgcn_mfma_f32_16x16x32_bf16(
            aW[mt], bX[nt].v, acc[mt][nt], 0, 0, 0);
  }

  #pragma unroll
  for (int mt = 0; mt < 4; mt++){
    const int ob = wm*64 + mt*16 + q*4;
    #pragma unroll
    for (int nt = 0; nt < 4; nt++){
      const int n = Nblk*128 + wn*64 + nt*16 + c;
      #pragma unroll
      for (int r = 0; r < 4; r++){
        u16 bv = (u16)f2bf_bits(acc[mt][nt][r]);
        int ol = ob + r;
        if (Mblk == 0){
          qfb[((size_t)b*NH_KD + ol)*NPTS + n] = bv;
        } else if (Mblk == 1){
          kb[(((size_t)b*NH + (ol >> 4))*NPTS + n)*16 + (ol & 15)] = bv;
        } else {
          int d = (Mblk - 2)*128 + ol;
          int p = (n & ~31) | (n & 3) | (((n >> 4) & 1) << 2) | (((n >> 2) & 3) << 3);
          vb[((size_t)b*DH + d)*NPTS + p] = bv;
        }
      }
    }
  }
}

// ---------------------------------------------------------------------------
// K2: depthwise 3x3x3 conv + scale/bias, x0.25 folded, bf16 in/out.
// ---------------------------------------------------------------------------
__global__ __launch_bounds__(512) void k_dw(
    const u16* __restrict__ qfb, const float* __restrict__ dww,
    const float* __restrict__ dws, const float* __restrict__ dwb,
    u16* __restrict__ qb)
{
  const int bc = blockIdx.x;            // b*128 + ch
  const int b  = bc >> 7;
  const int ch = bc & 127;
  const int n  = threadIdx.x;
  const int z = n >> 6, y = (n >> 3) & 7, xx = n & 7;
  float wv[27];
  #pragma unroll
  for (int i = 0; i < 27; i++) wv[i] = dww[ch*27 + i];
  const u16* qp = qfb + (size_t)bc * NPTS;
  float acc = 0.f;
  #pragma unroll
  for (int dz = 0; dz < 3; dz++){
    int zz = z + dz - 1; if ((unsigned)zz > 7u) continue;
    #pragma unroll
    for (int dy = 0; dy < 3; dy++){
      int yy = y + dy - 1; if ((unsigned)yy > 7u) continue;
      #pragma unroll
      for (int dx = 0; dx < 3; dx++){
        int xw = xx + dx - 1; if ((unsigned)xw > 7u) continue;
        acc += bf2f(qp[zz*64 + yy*8 + xw]) * wv[dz*9 + dy*3 + dx];
      }
    }
  }
  acc = (acc * dws[ch] + dwb[ch]) * 0.25f;   // fold 1/sqrt(KD)
  int hh = ch >> 4, cc = ch & 15;
  qb[(((size_t)b*NH + hh)*NPTS + n)*16 + cc] = (u16)f2bf_bits(acc);
}

// ---------------------------------------------------------------------------
// K_bias: bf16 bias table in TRANSPOSED-score C-layout:
// biasb[h][mtg 32][ntile 32][lane 64][r 4] u16, value = bias(m,n) with
// m = mtg*16 + (lane>>4)*4 + r, n = ntile*16 + (lane&15).
// ---------------------------------------------------------------------------
__global__ __launch_bounds__(256) void k_bias(
    const float* __restrict__ ab, const int* __restrict__ bidx,
    u32* __restrict__ biasb)
{
  const int blk = blockIdx.x;
  const int mtg = blk >> 5, ntile = blk & 31;
  const int lane = threadIdx.x & 63;
  const int h0 = threadIdx.x >> 6;
  const int qq = lane >> 4;
  const int n = ntile*16 + (lane & 15);
  int idx[4];
  #pragma unroll
  for (int r = 0; r < 4; r++)
    idx[r] = bidx[(size_t)n*NPTS + mtg*16 + qq*4 + r];
  for (int h = h0; h < NH; h += 4){
    float v0 = ab[h*NPTS + idx[0]], v1 = ab[h*NPTS + idx[1]];
    float v2 = ab[h*NPTS + idx[2]], v3 = ab[h*NPTS + idx[3]];
    u32* dst = biasb + (((size_t)(h*32 + mtg)*32 + ntile)*64 + lane)*2;
    dst[0] = pack2bf(v0, v1);
    dst[1] = pack2bf(v2, v3);
  }
}

// ---------------------------------------------------------------------------
// K3: LDS-free barrier-free MFMA flash attention, transposed scores.
// 2 n-tiles per wave (V frags shared). One-window-ahead prefetch of aK+bias;
// V loads at the top of the (ROLLED) window loop. R9 lesson: #pragma unroll
// on the window loop lets the scheduler hoist loads -> spill (WRITE blowup).
// Loop must stay rolled; the manual prefetch provides the overlap.
// ---------------------------------------------------------------------------
__global__ __launch_bounds__(256, 3) void k_attn(
    const u16* __restrict__ qb, const u16* __restrict__ kb,
    const u16* __restrict__ vb, const u16* __restrict__ biasb,
    u16* __restrict__ attnout)
{
  const int hb = blockIdx.x, tg = blockIdx.y;
  const int b = hb >> 3, h = hb & 7;
  const int lane = threadIdx.x & 63, wave = threadIdx.x >> 6;
  const int c = lane & 15, q = lane >> 4;
  const int bh = b*NH + h;
  const int nt0 = tg*8 + wave*2;        // ntiles {nt0, nt0+1}
  const int n0 = nt0*16;

  const bf16x8 zfrag = {0,0,0,0,0,0,0,0};
  bf16x8 bQ0 = zfrag, bQ1 = zfrag;
  if (q < 2){
    bQ0 = *(const bf16x8*)(qb + (((size_t)bh*NPTS + n0 + c) << 4) + q*8);
    bQ1 = *(const bf16x8*)(qb + (((size_t)bh*NPTS + n0 + 16 + c) << 4) + q*8);
  }

  const u16* kbh = kb + ((size_t)bh*NPTS)*16;
  const u16* vbh = vb + ((size_t)b*DH + h*DHEAD)*NPTS;
  const u16* bw0 = biasb + (size_t)h*262144 + (size_t)nt0*256 + lane*4;

  f32x4 O0[4] = {{0,0,0,0},{0,0,0,0},{0,0,0,0},{0,0,0,0}};
  f32x4 O1[4] = {{0,0,0,0},{0,0,0,0},{0,0,0,0},{0,0,0,0}};
  float ls0 = 0.f, ls1 = 0.f;

  // rotation registers: current window's aK + bias only (small!)
  bf16x8 aK0, aK1;
  uint2 u00, u01, u10, u11;

  auto loadKB = [&](int win, bf16x8& k0, bf16x8& k1,
                    uint2& x00, uint2& x01, uint2& x10, uint2& x11){
    const int mtg = win*2;
    if (q < 2){
      k0 = *(const bf16x8*)(kbh + (((size_t)(mtg*16 + c)) << 4) + q*8);
      k1 = *(const bf16x8*)(kbh + (((size_t)(mtg*16 + 16 + c)) << 4) + q*8);
    } else { k0 = zfrag; k1 = zfrag; }
    x00 = *(const uint2*)(bw0 + (size_t)mtg*8192);
    x01 = *(const uint2*)(bw0 + (size_t)(mtg+1)*8192);
    x10 = *(const uint2*)(bw0 + 256 + (size_t)mtg*8192);
    x11 = *(const uint2*)(bw0 + 256 + (size_t)(mtg+1)*8192);
  };

  loadKB(0, aK0, aK1, u00, u01, u10, u11);

  #pragma unroll 1
  for (int win = 0; win < 16; win++){
    // ---- V loads for THIS window issue first (latency covered below) ----
    const int mv = win*32 + q*8;
    bf16x8 V0 = *(const bf16x8*)(vbh + (size_t)( 0 + c)*NPTS + mv);
    bf16x8 V1 = *(const bf16x8*)(vbh + (size_t)(16 + c)*NPTS + mv);
    bf16x8 V2 = *(const bf16x8*)(vbh + (size_t)(32 + c)*NPTS + mv);
    bf16x8 V3 = *(const bf16x8*)(vbh + (size_t)(48 + c)*NPTS + mv);

    // ---- prefetch next window's aK/bias (small rotation state) ----
    bf16x8 nK0, nK1;
    uint2 m00, m01, m10, m11;
    if (win < 15)
      loadKB(win+1, nK0, nK1, m00, m01, m10, m11);

    // ---- scores: 2 m-tiles x 2 n-tiles ----
    f32x4 c00, c01, c10, c11;
    c00[0]=bflo(u00.x); c00[1]=bfhi(u00.x); c00[2]=bflo(u00.y); c00[3]=bfhi(u00.y);
    c01[0]=bflo(u01.x); c01[1]=bfhi(u01.x); c01[2]=bflo(u01.y); c01[3]=bfhi(u01.y);
    c10[0]=bflo(u10.x); c10[1]=bfhi(u10.x); c10[2]=bflo(u10.y); c10[3]=bfhi(u10.y);
    c11[0]=bflo(u11.x); c11[1]=bfhi(u11.x); c11[2]=bflo(u11.y); c11[3]=bfhi(u11.y);
    f32x4 S00 = __builtin_amdgcn_mfma_f32_16x16x32_bf16(aK0, bQ0, c00, 0, 0, 0);
    f32x4 S01 = __builtin_amdgcn_mfma_f32_16x16x32_bf16(aK1, bQ0, c01, 0, 0, 0);
    f32x4 S10 = __builtin_amdgcn_mfma_f32_16x16x32_bf16(aK0, bQ1, c10, 0, 0, 0);
    f32x4 S11 = __builtin_amdgcn_mfma_f32_16x16x32_bf16(aK1, bQ1, c11, 0, 0, 0);

    // ---- exp + pack into PV A-fragments ----
    float e0, e1, e2, e3;
    B8 aP0, aP1;
    e0 = __expf(S00[0]); e1 = __expf(S00[1]); e2 = __expf(S00[2]); e3 = __expf(S00[3]);
    ls0 += (e0 + e1) + (e2 + e3);
    aP0.u4.x = pack2bf(e0, e1); aP0.u4.y = pack2bf(e2, e3);
    e0 = __expf(S01[0]); e1 = __expf(S01[1]); e2 = __expf(S01[2]); e3 = __expf(S01[3]);
    ls0 += (e0 + e1) + (e2 + e3);
    aP0.u4.z = pack2bf(e0, e1); aP0.u4.w = pack2bf(e2, e3);
    e0 = __expf(S10[0]); e1 = __expf(S10[1]); e2 = __expf(S10[2]); e3 = __expf(S10[3]);
    ls1 += (e0 + e1) + (e2 + e3);
    aP1.u4.x = pack2bf(e0, e1); aP1.u4.y = pack2bf(e2, e3);
    e0 = __expf(S11[0]); e1 = __expf(S11[1]); e2 = __expf(S11[2]); e3 = __expf(S11[3]);
    ls1 += (e0 + e1) + (e2 + e3);
    aP1.u4.z = pack2bf(e0, e1); aP1.u4.w = pack2bf(e2, e3);

    // ---- PV: 4 d-tiles x 2 n-tiles, V shared ----
    O0[0] = __builtin_amdgcn_mfma_f32_16x16x32_bf16(aP0.v, V0, O0[0], 0, 0, 0);
    O1[0] = __builtin_amdgcn_mfma_f32_16x16x32_bf16(aP1.v, V0, O1[0], 0, 0, 0);
    O0[1] = __builtin_amdgcn_mfma_f32_16x16x32_bf16(aP0.v, V1, O0[1], 0, 0, 0);
    O1[1] = __builtin_amdgcn_mfma_f32_16x16x32_bf16(aP1.v, V1, O1[1], 0, 0, 0);
    O0[2] = __builtin_amdgcn_mfma_f32_16x16x32_bf16(aP0.v, V2, O0[2], 0, 0, 0);
    O1[2] = __builtin_amdgcn_mfma_f32_16x16x32_bf16(aP1.v, V2, O1[2], 0, 0, 0);
    O0[3] = __builtin_amdgcn_mfma_f32_16x16x32_bf16(aP0.v, V3, O0[3], 0, 0, 0);
    O1[3] = __builtin_amdgcn_mfma_f32_16x16x32_bf16(aP1.v, V3, O1[3], 0, 0, 0);

    // rotate
    aK0 = nK0; aK1 = nK1;
    u00 = m00; u01 = m01; u10 = m10; u11 = m11;
  }

  // ---- l reduction over the 4 m-quads ----
  ls0 += __shfl_xor(ls0, 16, 64);
  ls0 += __shfl_xor(ls0, 32, 64);
  ls1 += __shfl_xor(ls1, 16, 64);
  ls1 += __shfl_xor(ls1, 32, 64);
  f32x4 inv0, inv1;
  #pragma unroll
  for (int r = 0; r < 4; r++){
    inv0[r] = 1.0f / __shfl(ls0, q*4 + r, 64);
    inv1[r] = 1.0f / __shfl(ls1, q*4 + r, 64);
  }

  // ---- epilogue: relu(O/l) -> attn[b][n][dh] bf16 ----
  u16* ao = attnout + ((size_t)(b*NPTS + n0))*DH + h*DHEAD;
  #pragma unroll
  for (int dt = 0; dt < 4; dt++)
    #pragma unroll
    for (int r = 0; r < 4; r++){
      ao[(size_t)(q*4 + r)*DH + dt*16 + c] =
          (u16)f2bf_bits(fmaxf(O0[dt][r]*inv0[r], 0.f));
      ao[(size_t)(16 + q*4 + r)*DH + dt*16 + c] =
          (u16)f2bf_bits(fmaxf(O1[dt][r]*inv1[r], 0.f));
    }
}

// ---------------------------------------------------------------------------
// K4: proj MFMA GEMM (unchanged).
// ---------------------------------------------------------------------------
__global__ __launch_bounds__(256) void k_proj(
    const u16* __restrict__ attn, const u16* __restrict__ pwb,
    const float* __restrict__ bias, float* __restrict__ out)
{
  const int Mblk = blockIdx.x, Nblk = blockIdx.y, b = blockIdx.z;
  const int tid = threadIdx.x, wave = tid >> 6, lane = tid & 63;
  const int wm = wave >> 1, wn = wave & 1;
  const int c = lane & 15, q = lane >> 4;
  const int Mbase = Mblk*128 + wm*64;
  const int Nbase = Nblk*128 + wn*64;

  f32x4 acc[4][4];
  #pragma unroll
  for (int mt = 0; mt < 4; mt++){
    f32x4 bi;
    #pragma unroll
    for (int r = 0; r < 4; r++) bi[r] = bias[Mbase + mt*16 + q*4 + r];
    #pragma unroll
    for (int nt = 0; nt < 4; nt++) acc[mt][nt] = bi;
  }

  const u16* arow = attn + (size_t)b*NPTS*DH;

  for (int kc8 = 0; kc8 < 16; kc8++){
    const int kc = kc8*32;
    bf16x8 aW[4], bA[4];
    #pragma unroll
    for (int mt = 0; mt < 4; mt++)
      aW[mt] = *(const bf16x8*)(pwb + (size_t)(Mbase + mt*16 + c)*DH + kc + q*8);
    #pragma unroll
    for (int nt = 0; nt < 4; nt++)
      bA[nt] = *(const bf16x8*)(arow + (size_t)(Nbase + nt*16 + c)*DH + kc + q*8);
    #pragma unroll
    for (int mt = 0; mt < 4; mt++)
      #pragma unroll
      for (int nt = 0; nt < 4; nt++)
        acc[mt][nt] = __builtin_amdgcn_mfma_f32_16x16x32_bf16(
            aW[mt], bA[nt], acc[mt][nt], 0, 0, 0);
  }

  #pragma unroll
  for (int mt = 0; mt < 4; mt++){
    #pragma unroll
    for (int nt = 0; nt < 4; nt++){
      const int n = Nbase + nt*16 + c;
      #pragma unroll
      for (int r = 0; r < 4; r++){
        int o = Mbase + mt*16 + q*4 + r;
        out[((size_t)b*DIM + o)*NPTS + n] = acc[mt][nt][r];
      }
    }
  }
}

// ---------------------------------------------------------------------------
extern "C" void kernel_launch(void* const* d_in, const int* in_sizes, int n_in,
                              void* d_out, int out_size, void* d_ws, size_t ws_size,
                              hipStream_t stream)
{
  const float* x     = (const float*)d_in[0];
  const float* qkv_w = (const float*)d_in[1];
  const float* qkv_s = (const float*)d_in[2];
  const float* qkv_b = (const float*)d_in[3];
  const float* dw_w  = (const float*)d_in[4];
  const float* dw_s  = (const float*)d_in[5];
  const float* dw_b  = (const float*)d_in[6];
  const float* ab    = (const float*)d_in[7];
  const float* pw    = (const float*)d_in[8];
  const float* ps    = (const float*)d_in[9];
  const float* pb    = (const float*)d_in[10];
  const int* bidx    = (const int*)d_in[11];

  char* ws = (char*)d_ws;
  u16*   qfb   = (u16*)  (ws);                  //  4 MB (B,128,512) bf16
  u16*   qb    = (u16*)  (ws + ( 4u << 20));    //  4 MB (B,8,512,16) bf16
  u16*   kb    = (u16*)  (ws + ( 8u << 20));    //  4 MB (B,8,512,16) bf16
  u16*   vb    = (u16*)  (ws + (12u << 20));    // 16 MB (B,512,512) bf16 [b][d][p]
  u16*   attn  = (u16*)  (ws + (28u << 20));    // 16 MB (B,512,512) bf16 rows [n][dh]
  u32*   biasb = (u32*)  (ws + (44u << 20));    //  4 MB (8,32,32,64,4) bf16 S^T layout
  u32*   wqb   = (u32*)  (ws + (48u << 20));    // 384 KB (768,256) bf16
  u32*   pwb   = (u32*)  (ws + (49u << 20));    // 256 KB (256,512) bf16

  k_prep<<<dim3(640),      256, 0, stream>>>(qkv_w, qkv_s, pw, ps, wqb, pwb);
  k_qkv <<<dim3(6, 4, 32), 256, 0, stream>>>(x, (const u16*)wqb, qkv_b, qfb, kb, vb);
  k_dw  <<<dim3(32*128),   512, 0, stream>>>(qfb, dw_w, dw_s, dw_b, qb);
  k_bias<<<dim3(1024),     256, 0, stream>>>(ab, bidx, biasb);
  k_attn<<<dim3(256, 4),   256, 0, stream>>>(qb, kb, vb, (const u16*)biasb, attn);
  k_proj<<<dim3(2, 4, 32), 256, 0, stream>>>(attn, (const u16*)pwb, pb, (float*)d_out);
}

// Round 11
// 219.800 us; speedup vs baseline: 1.5784x; 1.0439x over previous
//
#include <hip/hip_runtime.h>

typedef unsigned int u32;
typedef unsigned short u16;
typedef __attribute__((ext_vector_type(8))) short bf16x8;
typedef __attribute__((ext_vector_type(4))) float f32x4;

constexpr int BATCH = 32;
constexpr int DIM   = 256;
constexpr int NPTS  = 512;
constexpr int NH    = 8;
constexpr int KD    = 16;
constexpr int DHEAD = 64;
constexpr int NH_KD = 128;
constexpr int DH    = 512;

__device__ __forceinline__ float bflo(u32 u){ return __uint_as_float(u << 16); }
__device__ __forceinline__ float bfhi(u32 u){ return __uint_as_float(u & 0xffff0000u); }
__device__ __forceinline__ float bf2f(u16 u){ return __uint_as_float(((u32)u) << 16); }
__device__ __forceinline__ u32 f2bf_bits(float f){
  u32 u = __float_as_uint(f);
  return (u + 0x7fffu + ((u >> 16) & 1u)) >> 16;
}
__device__ __forceinline__ u32 pack2bf(float a, float b){
  return f2bf_bits(a) | (f2bf_bits(b) << 16);
}

union B8 { bf16x8 v; uint2 u2[2]; uint4 u4; };

// ---------------------------------------------------------------------------
// K0: fold scale into weights, convert to bf16.
// ---------------------------------------------------------------------------
__global__ __launch_bounds__(256) void k_prep(
    const float* __restrict__ wq, const float* __restrict__ sq,
    const float* __restrict__ wp, const float* __restrict__ sp,
    u32* __restrict__ wqb, u32* __restrict__ pwb)
{
  int t = blockIdx.x * 256 + threadIdx.x;
  if (t < 98304){                      // 768*256/2
    int i = 2*t;
    float s = sq[i >> 8];
    wqb[t] = pack2bf(wq[i]*s, wq[i+1]*s);
  } else {
    int j = t - 98304;                 // 256*512/2
    int i = 2*j;
    float s = sp[i >> 9];
    pwb[j] = pack2bf(wp[i]*s, wp[i+1]*s);
  }
}

// ---------------------------------------------------------------------------
// K_xt: transpose x (fp32 [b][c 256][n 512]) -> xbt (bf16 rows [b][n][c]).
// 64x64 tiles via LDS (u16 stride 68 -> <=2-way bank aliasing, free).
// Grid 1024 = (b 32, ct 4, nt 8), block 256.
// ---------------------------------------------------------------------------
__global__ __launch_bounds__(256) void k_xt(
    const float* __restrict__ x, u16* __restrict__ xbt)
{
  __shared__ u16 T[64*68];
  const int blk = blockIdx.x;
  const int b = blk >> 5, ct = (blk >> 3) & 3, nt = blk & 7;
  const int t = threadIdx.x;
  const int c0 = ct*64, n0 = nt*64;

  const float* xb = x + ((size_t)b*DIM + c0)*NPTS + n0;
  #pragma unroll
  for (int it = 0; it < 4; it++){
    int cc = (t >> 4) + it*16;
    int nn = (t & 15) * 4;
    float4 v = *(const float4*)(xb + (size_t)cc*NPTS + nn);
    u32* dst = (u32*)&T[cc*68 + nn];
    dst[0] = pack2bf(v.x, v.y);
    dst[1] = pack2bf(v.z, v.w);
  }
  __syncthreads();
  u16* ob = xbt + ((size_t)b*NPTS + n0)*DIM + c0;
  #pragma unroll
  for (int it = 0; it < 4; it++){
    int nn = (t >> 4) + it*16;
    int cc = (t & 15) * 4;
    uint2 w;
    w.x = (u32)T[(cc+0)*68 + nn] | ((u32)T[(cc+1)*68 + nn] << 16);
    w.y = (u32)T[(cc+2)*68 + nn] | ((u32)T[(cc+3)*68 + nn] << 16);
    *(uint2*)(ob + (size_t)nn*DIM + cc) = w;
  }
}

// ---------------------------------------------------------------------------
// K1: qkv MFMA GEMM, LDS-free (k_proj structure). C[o 768][n 512] per b,
// K=256. A = wqb rows [o][k]; B = xbt rows [b][n][c] (both k-contiguous
// 16-B loads). Grid (Mblk 6, Nblk 4, b 32), block 256 = 4 waves (2x2).
// Epilogue scatter: Mblk0 -> qfb, 1 -> kb rows, 2-5 -> vb (m-permuted).
// ---------------------------------------------------------------------------
__global__ __launch_bounds__(256) void k_qkv(
    const u16* __restrict__ xbt, const u16* __restrict__ wqb,
    const float* __restrict__ bias,
    u16* __restrict__ qfb, u16* __restrict__ kb, u16* __restrict__ vb)
{
  const int Mblk = blockIdx.x, Nblk = blockIdx.y, b = blockIdx.z;
  const int tid = threadIdx.x, wave = tid >> 6, lane = tid & 63;
  const int wm = wave >> 1, wn = wave & 1;
  const int c = lane & 15, q = lane >> 4;
  const int Mbase = Mblk*128 + wm*64;
  const int Nbase = Nblk*128 + wn*64;

  f32x4 acc[4][4];
  #pragma unroll
  for (int mt = 0; mt < 4; mt++){
    f32x4 bi;
    #pragma unroll
    for (int r = 0; r < 4; r++) bi[r] = bias[Mbase + mt*16 + q*4 + r];
    #pragma unroll
    for (int nt = 0; nt < 4; nt++) acc[mt][nt] = bi;
  }

  const u16* xrow = xbt + (size_t)b*NPTS*DIM;

  for (int kc8 = 0; kc8 < 8; kc8++){
    const int kc = kc8*32;
    bf16x8 aW[4], bX[4];
    #pragma unroll
    for (int mt = 0; mt < 4; mt++)
      aW[mt] = *(const bf16x8*)(wqb + (size_t)(Mbase + mt*16 + c)*DIM + kc + q*8);
    #pragma unroll
    for (int nt = 0; nt < 4; nt++)
      bX[nt] = *(const bf16x8*)(xrow + (size_t)(Nbase + nt*16 + c)*DIM + kc + q*8);
    #pragma unroll
    for (int mt = 0; mt < 4; mt++)
      #pragma unroll
      for (int nt = 0; nt < 4; nt++)
        acc[mt][nt] = __builtin_amdgcn_mfma_f32_16x16x32_bf16(
            aW[mt], bX[nt], acc[mt][nt], 0, 0, 0);
  }

  #pragma unroll
  for (int mt = 0; mt < 4; mt++){
    const int ob = wm*64 + mt*16 + q*4;
    #pragma unroll
    for (int nt = 0; nt < 4; nt++){
      const int n = Nbase + nt*16 + c;
      #pragma unroll
      for (int r = 0; r < 4; r++){
        u16 bv = (u16)f2bf_bits(acc[mt][nt][r]);
        int ol = ob + r;
        if (Mblk == 0){
          qfb[((size_t)b*NH_KD + ol)*NPTS + n] = bv;
        } else if (Mblk == 1){
          kb[(((size_t)b*NH + (ol >> 4))*NPTS + n)*16 + (ol & 15)] = bv;
        } else {
          int d = (Mblk - 2)*128 + ol;
          int p = (n & ~31) | (n & 3) | (((n >> 4) & 1) << 2) | (((n >> 2) & 3) << 3);
          vb[((size_t)b*DH + d)*NPTS + p] = bv;
        }
      }
    }
  }
}

// ---------------------------------------------------------------------------
// K2: depthwise 3x3x3 conv + scale/bias, x0.25 folded, bf16 in/out.
// ---------------------------------------------------------------------------
__global__ __launch_bounds__(512) void k_dw(
    const u16* __restrict__ qfb, const float* __restrict__ dww,
    const float* __restrict__ dws, const float* __restrict__ dwb,
    u16* __restrict__ qb)
{
  const int bc = blockIdx.x;            // b*128 + ch
  const int b  = bc >> 7;
  const int ch = bc & 127;
  const int n  = threadIdx.x;
  const int z = n >> 6, y = (n >> 3) & 7, xx = n & 7;
  float wv[27];
  #pragma unroll
  for (int i = 0; i < 27; i++) wv[i] = dww[ch*27 + i];
  const u16* qp = qfb + (size_t)bc * NPTS;
  float acc = 0.f;
  #pragma unroll
  for (int dz = 0; dz < 3; dz++){
    int zz = z + dz - 1; if ((unsigned)zz > 7u) continue;
    #pragma unroll
    for (int dy = 0; dy < 3; dy++){
      int yy = y + dy - 1; if ((unsigned)yy > 7u) continue;
      #pragma unroll
      for (int dx = 0; dx < 3; dx++){
        int xw = xx + dx - 1; if ((unsigned)xw > 7u) continue;
        acc += bf2f(qp[zz*64 + yy*8 + xw]) * wv[dz*9 + dy*3 + dx];
      }
    }
  }
  acc = (acc * dws[ch] + dwb[ch]) * 0.25f;   // fold 1/sqrt(KD)
  int hh = ch >> 4, cc = ch & 15;
  qb[(((size_t)b*NH + hh)*NPTS + n)*16 + cc] = (u16)f2bf_bits(acc);
}

// ---------------------------------------------------------------------------
// K_bias: bf16 bias table in TRANSPOSED-score C-layout:
// biasb[h][mtg 32][ntile 32][lane 64][r 4] u16, value = bias(m,n) with
// m = mtg*16 + (lane>>4)*4 + r, n = ntile*16 + (lane&15).
// ---------------------------------------------------------------------------
__global__ __launch_bounds__(256) void k_bias(
    const float* __restrict__ ab, const int* __restrict__ bidx,
    u32* __restrict__ biasb)
{
  const int blk = blockIdx.x;
  const int mtg = blk >> 5, ntile = blk & 31;
  const int lane = threadIdx.x & 63;
  const int h0 = threadIdx.x >> 6;
  const int qq = lane >> 4;
  const int n = ntile*16 + (lane & 15);
  int idx[4];
  #pragma unroll
  for (int r = 0; r < 4; r++)
    idx[r] = bidx[(size_t)n*NPTS + mtg*16 + qq*4 + r];
  for (int h = h0; h < NH; h += 4){
    float v0 = ab[h*NPTS + idx[0]], v1 = ab[h*NPTS + idx[1]];
    float v2 = ab[h*NPTS + idx[2]], v3 = ab[h*NPTS + idx[3]];
    u32* dst = biasb + (((size_t)(h*32 + mtg)*32 + ntile)*64 + lane)*2;
    dst[0] = pack2bf(v0, v1);
    dst[1] = pack2bf(v2, v3);
  }
}

// ---------------------------------------------------------------------------
// K3: LDS-free barrier-free MFMA flash attention, transposed scores.
// 2 n-tiles per wave (V frags shared). One-window-ahead prefetch of aK+bias;
// V loads at the top of the ROLLED window loop (R9/R10 lesson: unrolling the
// window loop lets the scheduler hoist loads -> scratch spill).
// ---------------------------------------------------------------------------
__global__ __launch_bounds__(256, 3) void k_attn(
    const u16* __restrict__ qb, const u16* __restrict__ kb,
    const u16* __restrict__ vb, const u16* __restrict__ biasb,
    u16* __restrict__ attnout)
{
  const int hb = blockIdx.x, tg = blockIdx.y;
  const int b = hb >> 3, h = hb & 7;
  const int lane = threadIdx.x & 63, wave = threadIdx.x >> 6;
  const int c = lane & 15, q = lane >> 4;
  const int bh = b*NH + h;
  const int nt0 = tg*8 + wave*2;        // ntiles {nt0, nt0+1}
  const int n0 = nt0*16;

  const bf16x8 zfrag = {0,0,0,0,0,0,0,0};
  bf16x8 bQ0 = zfrag, bQ1 = zfrag;
  if (q < 2){
    bQ0 = *(const bf16x8*)(qb + (((size_t)bh*NPTS + n0 + c) << 4) + q*8);
    bQ1 = *(const bf16x8*)(qb + (((size_t)bh*NPTS + n0 + 16 + c) << 4) + q*8);
  }

  const u16* kbh = kb + ((size_t)bh*NPTS)*16;
  const u16* vbh = vb + ((size_t)b*DH + h*DHEAD)*NPTS;
  const u16* bw0 = biasb + (size_t)h*262144 + (size_t)nt0*256 + lane*4;

  f32x4 O0[4] = {{0,0,0,0},{0,0,0,0},{0,0,0,0},{0,0,0,0}};
  f32x4 O1[4] = {{0,0,0,0},{0,0,0,0},{0,0,0,0},{0,0,0,0}};
  float ls0 = 0.f, ls1 = 0.f;

  bf16x8 aK0, aK1;
  uint2 u00, u01, u10, u11;

  auto loadKB = [&](int win, bf16x8& k0, bf16x8& k1,
                    uint2& x00, uint2& x01, uint2& x10, uint2& x11){
    const int mtg = win*2;
    if (q < 2){
      k0 = *(const bf16x8*)(kbh + (((size_t)(mtg*16 + c)) << 4) + q*8);
      k1 = *(const bf16x8*)(kbh + (((size_t)(mtg*16 + 16 + c)) << 4) + q*8);
    } else { k0 = zfrag; k1 = zfrag; }
    x00 = *(const uint2*)(bw0 + (size_t)mtg*8192);
    x01 = *(const uint2*)(bw0 + (size_t)(mtg+1)*8192);
    x10 = *(const uint2*)(bw0 + 256 + (size_t)mtg*8192);
    x11 = *(const uint2*)(bw0 + 256 + (size_t)(mtg+1)*8192);
  };

  loadKB(0, aK0, aK1, u00, u01, u10, u11);

  #pragma unroll 1
  for (int win = 0; win < 16; win++){
    const int mv = win*32 + q*8;
    bf16x8 V0 = *(const bf16x8*)(vbh + (size_t)( 0 + c)*NPTS + mv);
    bf16x8 V1 = *(const bf16x8*)(vbh + (size_t)(16 + c)*NPTS + mv);
    bf16x8 V2 = *(const bf16x8*)(vbh + (size_t)(32 + c)*NPTS + mv);
    bf16x8 V3 = *(const bf16x8*)(vbh + (size_t)(48 + c)*NPTS + mv);

    bf16x8 nK0, nK1;
    uint2 m00, m01, m10, m11;
    if (win < 15)
      loadKB(win+1, nK0, nK1, m00, m01, m10, m11);

    f32x4 c00, c01, c10, c11;
    c00[0]=bflo(u00.x); c00[1]=bfhi(u00.x); c00[2]=bflo(u00.y); c00[3]=bfhi(u00.y);
    c01[0]=bflo(u01.x); c01[1]=bfhi(u01.x); c01[2]=bflo(u01.y); c01[3]=bfhi(u01.y);
    c10[0]=bflo(u10.x); c10[1]=bfhi(u10.x); c10[2]=bflo(u10.y); c10[3]=bfhi(u10.y);
    c11[0]=bflo(u11.x); c11[1]=bfhi(u11.x); c11[2]=bflo(u11.y); c11[3]=bfhi(u11.y);
    f32x4 S00 = __builtin_amdgcn_mfma_f32_16x16x32_bf16(aK0, bQ0, c00, 0, 0, 0);
    f32x4 S01 = __builtin_amdgcn_mfma_f32_16x16x32_bf16(aK1, bQ0, c01, 0, 0, 0);
    f32x4 S10 = __builtin_amdgcn_mfma_f32_16x16x32_bf16(aK0, bQ1, c10, 0, 0, 0);
    f32x4 S11 = __builtin_amdgcn_mfma_f32_16x16x32_bf16(aK1, bQ1, c11, 0, 0, 0);

    float e0, e1, e2, e3;
    B8 aP0, aP1;
    e0 = __expf(S00[0]); e1 = __expf(S00[1]); e2 = __expf(S00[2]); e3 = __expf(S00[3]);
    ls0 += (e0 + e1) + (e2 + e3);
    aP0.u4.x = pack2bf(e0, e1); aP0.u4.y = pack2bf(e2, e3);
    e0 = __expf(S01[0]); e1 = __expf(S01[1]); e2 = __expf(S01[2]); e3 = __expf(S01[3]);
    ls0 += (e0 + e1) + (e2 + e3);
    aP0.u4.z = pack2bf(e0, e1); aP0.u4.w = pack2bf(e2, e3);
    e0 = __expf(S10[0]); e1 = __expf(S10[1]); e2 = __expf(S10[2]); e3 = __expf(S10[3]);
    ls1 += (e0 + e1) + (e2 + e3);
    aP1.u4.x = pack2bf(e0, e1); aP1.u4.y = pack2bf(e2, e3);
    e0 = __expf(S11[0]); e1 = __expf(S11[1]); e2 = __expf(S11[2]); e3 = __expf(S11[3]);
    ls1 += (e0 + e1) + (e2 + e3);
    aP1.u4.z = pack2bf(e0, e1); aP1.u4.w = pack2bf(e2, e3);

    O0[0] = __builtin_amdgcn_mfma_f32_16x16x32_bf16(aP0.v, V0, O0[0], 0, 0, 0);
    O1[0] = __builtin_amdgcn_mfma_f32_16x16x32_bf16(aP1.v, V0, O1[0], 0, 0, 0);
    O0[1] = __builtin_amdgcn_mfma_f32_16x16x32_bf16(aP0.v, V1, O0[1], 0, 0, 0);
    O1[1] = __builtin_amdgcn_mfma_f32_16x16x32_bf16(aP1.v, V1, O1[1], 0, 0, 0);
    O0[2] = __builtin_amdgcn_mfma_f32_16x16x32_bf16(aP0.v, V2, O0[2], 0, 0, 0);
    O1[2] = __builtin_amdgcn_mfma_f32_16x16x32_bf16(aP1.v, V2, O1[2], 0, 0, 0);
    O0[3] = __builtin_amdgcn_mfma_f32_16x16x32_bf16(aP0.v, V3, O0[3], 0, 0, 0);
    O1[3] = __builtin_amdgcn_mfma_f32_16x16x32_bf16(aP1.v, V3, O1[3], 0, 0, 0);

    aK0 = nK0; aK1 = nK1;
    u00 = m00; u01 = m01; u10 = m10; u11 = m11;
  }

  ls0 += __shfl_xor(ls0, 16, 64);
  ls0 += __shfl_xor(ls0, 32, 64);
  ls1 += __shfl_xor(ls1, 16, 64);
  ls1 += __shfl_xor(ls1, 32, 64);
  f32x4 inv0, inv1;
  #pragma unroll
  for (int r = 0; r < 4; r++){
    inv0[r] = 1.0f / __shfl(ls0, q*4 + r, 64);
    inv1[r] = 1.0f / __shfl(ls1, q*4 + r, 64);
  }

  u16* ao = attnout + ((size_t)(b*NPTS + n0))*DH + h*DHEAD;
  #pragma unroll
  for (int dt = 0; dt < 4; dt++)
    #pragma unroll
    for (int r = 0; r < 4; r++){
      ao[(size_t)(q*4 + r)*DH + dt*16 + c] =
          (u16)f2bf_bits(fmaxf(O0[dt][r]*inv0[r], 0.f));
      ao[(size_t)(16 + q*4 + r)*DH + dt*16 + c] =
          (u16)f2bf_bits(fmaxf(O1[dt][r]*inv1[r], 0.f));
    }
}

// ---------------------------------------------------------------------------
// K4: proj MFMA GEMM (unchanged).
// ---------------------------------------------------------------------------
__global__ __launch_bounds__(256) void k_proj(
    const u16* __restrict__ attn, const u16* __restrict__ pwb,
    const float* __restrict__ bias, float* __restrict__ out)
{
  const int Mblk = blockIdx.x, Nblk = blockIdx.y, b = blockIdx.z;
  const int tid = threadIdx.x, wave = tid >> 6, lane = tid & 63;
  const int wm = wave >> 1, wn = wave & 1;
  const int c = lane & 15, q = lane >> 4;
  const int Mbase = Mblk*128 + wm*64;
  const int Nbase = Nblk*128 + wn*64;

  f32x4 acc[4][4];
  #pragma unroll
  for (int mt = 0; mt < 4; mt++){
    f32x4 bi;
    #pragma unroll
    for (int r = 0; r < 4; r++) bi[r] = bias[Mbase + mt*16 + q*4 + r];
    #pragma unroll
    for (int nt = 0; nt < 4; nt++) acc[mt][nt] = bi;
  }

  const u16* arow = attn + (size_t)b*NPTS*DH;

  for (int kc8 = 0; kc8 < 16; kc8++){
    const int kc = kc8*32;
    bf16x8 aW[4], bA[4];
    #pragma unroll
    for (int mt = 0; mt < 4; mt++)
      aW[mt] = *(const bf16x8*)(pwb + (size_t)(Mbase + mt*16 + c)*DH + kc + q*8);
    #pragma unroll
    for (int nt = 0; nt < 4; nt++)
      bA[nt] = *(const bf16x8*)(arow + (size_t)(Nbase + nt*16 + c)*DH + kc + q*8);
    #pragma unroll
    for (int mt = 0; mt < 4; mt++)
      #pragma unroll
      for (int nt = 0; nt < 4; nt++)
        acc[mt][nt] = __builtin_amdgcn_mfma_f32_16x16x32_bf16(
            aW[mt], bA[nt], acc[mt][nt], 0, 0, 0);
  }

  #pragma unroll
  for (int mt = 0; mt < 4; mt++){
    #pragma unroll
    for (int nt = 0; nt < 4; nt++){
      const int n = Nbase + nt*16 + c;
      #pragma unroll
      for (int r = 0; r < 4; r++){
        int o = Mbase + mt*16 + q*4 + r;
        out[((size_t)b*DIM + o)*NPTS + n] = acc[mt][nt][r];
      }
    }
  }
}

// ---------------------------------------------------------------------------
extern "C" void kernel_launch(void* const* d_in, const int* in_sizes, int n_in,
                              void* d_out, int out_size, void* d_ws, size_t ws_size,
                              hipStream_t stream)
{
  const float* x     = (const float*)d_in[0];
  const float* qkv_w = (const float*)d_in[1];
  const float* qkv_s = (const float*)d_in[2];
  const float* qkv_b = (const float*)d_in[3];
  const float* dw_w  = (const float*)d_in[4];
  const float* dw_s  = (const float*)d_in[5];
  const float* dw_b  = (const float*)d_in[6];
  const float* ab    = (const float*)d_in[7];
  const float* pw    = (const float*)d_in[8];
  const float* ps    = (const float*)d_in[9];
  const float* pb    = (const float*)d_in[10];
  const int* bidx    = (const int*)d_in[11];

  char* ws = (char*)d_ws;
  u16*   qfb   = (u16*)  (ws);                  //  4 MB (B,128,512) bf16
  u16*   qb    = (u16*)  (ws + ( 4u << 20));    //  4 MB (B,8,512,16) bf16
  u16*   kb    = (u16*)  (ws + ( 8u << 20));    //  4 MB (B,8,512,16) bf16
  u16*   vb    = (u16*)  (ws + (12u << 20));    // 16 MB (B,512,512) bf16 [b][d][p]
  u16*   attn  = (u16*)  (ws + (28u << 20));    // 16 MB (B,512,512) bf16 rows [n][dh]
  u32*   biasb = (u32*)  (ws + (44u << 20));    //  4 MB (8,32,32,64,4) bf16 S^T layout
  u32*   wqb   = (u32*)  (ws + (48u << 20));    // 384 KB (768,256) bf16
  u32*   pwb   = (u32*)  (ws + (49u << 20));    // 256 KB (256,512) bf16
  u16*   xbt   = (u16*)  (ws + (50u << 20));    //  8 MB (B,512,256) bf16 rows

  k_prep<<<dim3(640),      256, 0, stream>>>(qkv_w, qkv_s, pw, ps, wqb, pwb);
  k_xt  <<<dim3(1024),     256, 0, stream>>>(x, xbt);
  k_qkv <<<dim3(6, 4, 32), 256, 0, stream>>>(xbt, (const u16*)wqb, qkv_b, qfb, kb, vb);
  k_dw  <<<dim3(32*128),   512, 0, stream>>>(qfb, dw_w, dw_s, dw_b, qb);
  k_bias<<<dim3(1024),     256, 0, stream>>>(ab, bidx, biasb);
  k_attn<<<dim3(256, 4),   256, 0, stream>>>(qb, kb, vb, (const u16*)biasb, attn);
  k_proj<<<dim3(2, 4, 32), 256, 0, stream>>>(attn, (const u16*)pwb, pb, (float*)d_out);
}